// Round 9
// baseline (237.824 us; speedup 1.0000x reference)
//
#include <hip/hip_runtime.h>

#define NN 50000
#define EE 800000
#define SCAN_BLOCKS 49  // 49*1024 >= 50000
#define LOG2E 1.44269504088896340736f

typedef __attribute__((ext_vector_type(4))) float f32x4;
typedef __attribute__((ext_vector_type(8))) short bf16x8;
typedef unsigned int u32;
#define GLOBAL_AS __attribute__((address_space(1)))
#define LDS_AS __attribute__((address_space(3)))

static __device__ __forceinline__ u32 cvtpk_bf16(float lo, float hi) {
  u32 r;
  asm("v_cvt_pk_bf16_f32 %0, %1, %2" : "=v"(r) : "v"(lo), "v"(hi));
  return r;
}
static __device__ __forceinline__ unsigned short f2bf_hw(float f) {
  return (unsigned short)cvtpk_bf16(f, 0.f);
}
static __device__ __forceinline__ float bfl(unsigned int u) { return __uint_as_float(u << 16); }
static __device__ __forceinline__ float bfh(unsigned int u) { return __uint_as_float(u & 0xFFFF0000u); }

// ---- prep: conv W->bf16 | att scales | edge histogram (x-conv folded into GEMM) ----
__global__ void k_prep(const float4* __restrict__ Wl, const float4* __restrict__ Wr,
                       const float4* __restrict__ Ws, const float* __restrict__ att,
                       const int* __restrict__ ei,
                       uint2* __restrict__ wb2,
                       float* __restrict__ av6, float* __restrict__ av04,
                       int* __restrict__ counts) {
  int b = blockIdx.x;
  if (b < 192) {
    int i = b * 256 + threadIdx.x;  // over 49152
    if (i < 49152) {
      int which = i >> 14;
      int idx = i & 16383;
      const float4* W = (which == 0) ? Wl : (which == 1) ? Wr : Ws;
      float4 v = W[idx];
      uint2 o;
      o.x = cvtpk_bf16(v.x, v.y);
      o.y = cvtpk_bf16(v.z, v.w);
      wb2[i] = o;
    }
  } else if (b == 192) {
    float a = att[threadIdx.x];
    av6[threadIdx.x] = 0.6f * LOG2E * a;
    av04[threadIdx.x] = 0.4f * LOG2E * a;
  } else {
    int e = (b - 193) * 256 + threadIdx.x;
    if (e < EE) atomicAdd(&counts[ei[EE + e]], 1);
  }
}

// ---- hierarchical scan (counts+1 folds in the self-loop) ----
__global__ __launch_bounds__(1024) void k_scan1(const int* __restrict__ counts,
                                                int* __restrict__ partial,
                                                int* __restrict__ blockSums) {
  __shared__ int tmp[1024];
  int t = threadIdx.x;
  int i = blockIdx.x * 1024 + t;
  int v = (i < NN) ? (counts[i] + 1) : 0;
  tmp[t] = v;
  __syncthreads();
  for (int off = 1; off < 1024; off <<= 1) {
    int u = (t >= off) ? tmp[t - off] : 0;
    __syncthreads();
    tmp[t] += u;
    __syncthreads();
  }
  if (i < NN) partial[i] = tmp[t] - v;  // exclusive within block
  if (t == 1023) blockSums[blockIdx.x] = tmp[1023];
}

// ---- block offsets (wave-reduced) -> ptr/cursor; self-loop placed here ----
__global__ __launch_bounds__(1024) void k_scan3(const int* __restrict__ partial,
                                                const int* __restrict__ blockSums,
                                                int* __restrict__ ptr,
                                                int* __restrict__ cursor,
                                                int* __restrict__ csr) {
  __shared__ int boff;
  if (threadIdx.x < 64) {
    int v = (threadIdx.x < blockIdx.x) ? blockSums[threadIdx.x] : 0;
    v += __shfl_xor(v, 1);
    v += __shfl_xor(v, 2);
    v += __shfl_xor(v, 4);
    v += __shfl_xor(v, 8);
    v += __shfl_xor(v, 16);
    v += __shfl_xor(v, 32);
    if (threadIdx.x == 0) boff = v;
  }
  __syncthreads();
  int i = blockIdx.x * 1024 + threadIdx.x;
  if (i < NN) {
    int v = partial[i] + boff;
    ptr[i] = v;
    csr[v] = i;          // self-loop occupies first slot
    cursor[i] = v + 1;   // real edges start after it
    if (i == NN - 1) ptr[NN] = EE + NN;
  }
}

// ---- scatter: own kernel (full occupancy), 2 edges/thread for atomic MLP ----
__global__ __launch_bounds__(256) void k_scatter(const int* __restrict__ ei,
                                                 int* __restrict__ cursor,
                                                 int* __restrict__ csr) {
  int t = blockIdx.x * 256 + threadIdx.x;
  if (t >= EE / 2) return;
  int e0 = t, e1 = t + EE / 2;
  int d0 = ei[EE + e0];
  int d1 = ei[EE + e1];
  int p0 = atomicAdd(&cursor[d0], 1);
  int p1 = atomicAdd(&cursor[d1], 1);
  csr[p0] = ei[e0];
  csr[p1] = ei[e1];
}

// ---- GEMM: A = x (f32, converted in-staging), B = wb; grid (col, row) for A L3 reuse ----
// A: reg-staged (ldx4 f32 ->cvt_pk-> ds_write_b128 at linear slot, source pre-swizzled);
// B: global_load_lds DMA (linear dest, pre-swizzled source). Read side: same XOR swizzle.
__global__ __launch_bounds__(256) void k_gemm(const float* __restrict__ x,
                                              const unsigned short* __restrict__ wb,
                                              unsigned short* __restrict__ xlb,
                                              unsigned short* __restrict__ zb) {
  __shared__ alignas(16) unsigned short As[128 * 64];
  __shared__ alignas(16) unsigned short Bs[128 * 64];
  const int tid = threadIdx.x;
  const int lane = tid & 63;
  const int wave = tid >> 6;
  const int wr = wave >> 1, wc = wave & 1;
  const int rbase = blockIdx.y * 128;
  const int cbase = blockIdx.x * 128;
  const int rl = lane & 15;
  const int q = lane >> 4;

  f32x4 acc[4][4];
#pragma unroll
  for (int a = 0; a < 4; ++a)
#pragma unroll
    for (int b = 0; b < 4; ++b) acc[a][b] = (f32x4){0.f, 0.f, 0.f, 0.f};

  for (int kt = 0; kt < 256; kt += 64) {
#pragma unroll
    for (int i = 0; i < 4; ++i) {
      int c = tid + i * 256;            // chunk id: 1024 chunks of 16B per buffer
      int row = c >> 3, kcx = c & 7;    // kcx = physical (linear LDS) slot
      int kc = kcx ^ (row & 7);         // logical k-chunk living in slot kcx
      int gr = rbase + row; if (gr > NN - 1) gr = NN - 1;
      // A: 8 f32 -> 8 bf16 -> 16B ds_write at linear byte addr c*16
      const float4* srcA = (const float4*)(x + (size_t)gr * 256 + kt + kc * 8);
      float4 a0 = srcA[0], a1 = srcA[1];
      uint4 pk;
      pk.x = cvtpk_bf16(a0.x, a0.y); pk.y = cvtpk_bf16(a0.z, a0.w);
      pk.z = cvtpk_bf16(a1.x, a1.y); pk.w = cvtpk_bf16(a1.z, a1.w);
      *(uint4*)((char*)As + c * 16) = pk;
      // B: DMA 16B
      int ldsoff = i * 4096 + wave * 1024;  // wave-uniform byte base
      __builtin_amdgcn_global_load_lds(
          (const GLOBAL_AS u32*)(wb + (size_t)(cbase + row) * 256 + kt + kc * 8),
          (LDS_AS u32*)((LDS_AS char*)Bs + ldsoff), 16, 0, 0);
    }
    __syncthreads();
#pragma unroll
    for (int ks = 0; ks < 2; ++ks) {
      bf16x8 af[4], bf[4];
      int kc = ks * 4 + q;
#pragma unroll
      for (int t = 0; t < 4; ++t) {
        int ra = wr * 64 + t * 16 + rl;
        af[t] = *(const bf16x8*)((const char*)As + ra * 128 + ((kc << 4) ^ ((ra & 7) << 4)));
        int rb = wc * 64 + t * 16 + rl;
        bf[t] = *(const bf16x8*)((const char*)Bs + rb * 128 + ((kc << 4) ^ ((rb & 7) << 4)));
      }
#pragma unroll
      for (int a = 0; a < 4; ++a)
#pragma unroll
        for (int b = 0; b < 4; ++b)
          acc[a][b] = __builtin_amdgcn_mfma_f32_16x16x32_bf16(af[a], bf[b], acc[a][b], 0, 0, 0);
    }
    __syncthreads();
  }
  const bool isxl = (cbase < 256);
#pragma unroll
  for (int a = 0; a < 4; ++a) {
#pragma unroll
    for (int j = 0; j < 4; ++j) {
      int row = rbase + wr * 64 + a * 16 + q * 4 + j;
      if (row < NN) {
#pragma unroll
        for (int b = 0; b < 4; ++b) {
          int col = cbase + wc * 64 + b * 16 + rl;
          if (isxl)
            xlb[(size_t)row * 256 + col] = f2bf_hw(acc[a][b][j]);
          else
            zb[(size_t)row * 512 + (col - 256)] = f2bf_hw(acc[a][b][j]);
        }
      }
    }
  }
}

// ---- per-node FLAT-softmax aggregation + epilogue (4-deep, 32 VGPR) ----
#define LOGIT6(ex, ey, ez, ew, p)                                      \
  t = ex + xrx; p = a6.x * t;         p = fmaf(a04.x, fabsf(t), p);    \
  t = ey + xry; p = fmaf(a6.y, t, p); p = fmaf(a04.y, fabsf(t), p);    \
  t = ez + xrz; p = fmaf(a6.z, t, p); p = fmaf(a04.z, fabsf(t), p);    \
  t = ew + xrw; p = fmaf(a6.w, t, p); p = fmaf(a04.w, fabsf(t), p);

__global__ __launch_bounds__(256) void k_agg(const uint2* __restrict__ xl2,
                                             const uint2* __restrict__ zb2,
                                             const int* __restrict__ ptr,
                                             const int* __restrict__ csr,
                                             const float* __restrict__ av6,
                                             const float* __restrict__ av04,
                                             const float* __restrict__ bias,
                                             float* __restrict__ out) {
  int node = blockIdx.x * 4 + (threadIdx.x >> 6);
  if (node >= NN) return;
  int lane = threadIdx.x & 63;

  uint2 xrv = zb2[(size_t)node * 128 + lane];
  float xrx = bfl(xrv.x), xry = bfh(xrv.x), xrz = bfl(xrv.y), xrw = bfh(xrv.y);
  const float4 a6 = *(const float4*)(av6 + lane * 4);
  const float4 a04 = *(const float4*)(av04 + lane * 4);

  float sA = 0.f, axA = 0.f, ayA = 0.f, azA = 0.f, awA = 0.f;
  float sB = 0.f, axB = 0.f, ayB = 0.f, azB = 0.f, awB = 0.f;
  int beg = ptr[node], end = ptr[node + 1];
  int i = beg;
  for (; i + 4 <= end; i += 4) {
    int s0 = csr[i], s1 = csr[i + 1], s2 = csr[i + 2], s3 = csr[i + 3];
    uint2 v0 = xl2[(size_t)s0 * 64 + lane];
    uint2 v1 = xl2[(size_t)s1 * 64 + lane];
    uint2 v2 = xl2[(size_t)s2 * 64 + lane];
    uint2 v3 = xl2[(size_t)s3 * 64 + lane];
    float e0x = bfl(v0.x), e0y = bfh(v0.x), e0z = bfl(v0.y), e0w = bfh(v0.y);
    float e1x = bfl(v1.x), e1y = bfh(v1.x), e1z = bfl(v1.y), e1w = bfh(v1.y);
    float e2x = bfl(v2.x), e2y = bfh(v2.x), e2z = bfl(v2.y), e2w = bfh(v2.y);
    float e3x = bfl(v3.x), e3y = bfh(v3.x), e3z = bfl(v3.y), e3w = bfh(v3.y);
    float t, p0, p1, p2, p3;
    LOGIT6(e0x, e0y, e0z, e0w, p0)
    LOGIT6(e1x, e1y, e1z, e1w, p1)
    LOGIT6(e2x, e2y, e2z, e2w, p2)
    LOGIT6(e3x, e3y, e3z, e3w, p3)
    p0 += __shfl_xor(p0, 1); p1 += __shfl_xor(p1, 1);
    p2 += __shfl_xor(p2, 1); p3 += __shfl_xor(p3, 1);
    p0 += __shfl_xor(p0, 2); p1 += __shfl_xor(p1, 2);
    p2 += __shfl_xor(p2, 2); p3 += __shfl_xor(p3, 2);
    p0 += __shfl_xor(p0, 4); p1 += __shfl_xor(p1, 4);
    p2 += __shfl_xor(p2, 4); p3 += __shfl_xor(p3, 4);
    p0 = exp2f(p0); p1 = exp2f(p1); p2 = exp2f(p2); p3 = exp2f(p3);
    sA += p0;  axA += p0 * e0x; ayA += p0 * e0y; azA += p0 * e0z; awA += p0 * e0w;
    sB += p1;  axB += p1 * e1x; ayB += p1 * e1y; azB += p1 * e1z; awB += p1 * e1w;
    sA += p2;  axA += p2 * e2x; ayA += p2 * e2y; azA += p2 * e2z; awA += p2 * e2w;
    sB += p3;  axB += p3 * e3x; ayB += p3 * e3y; azB += p3 * e3z; awB += p3 * e3w;
  }
  for (; i < end; ++i) {
    int s0 = csr[i];
    uint2 v0 = xl2[(size_t)s0 * 64 + lane];
    float e0x = bfl(v0.x), e0y = bfh(v0.x), e0z = bfl(v0.y), e0w = bfh(v0.y);
    float t, p0;
    LOGIT6(e0x, e0y, e0z, e0w, p0)
    p0 += __shfl_xor(p0, 1);
    p0 += __shfl_xor(p0, 2);
    p0 += __shfl_xor(p0, 4);
    p0 = exp2f(p0);
    sA += p0;  axA += p0 * e0x; ayA += p0 * e0y; azA += p0 * e0z; awA += p0 * e0w;
  }
  float inv = 1.f / (sA + sB);
  uint2 skv = zb2[(size_t)node * 128 + 64 + lane];
  const float4 bv = *(const float4*)(bias + lane * 4);
  float4 o;
  o.x = (axA + axB) * inv + bv.x; o.x = (o.x > 0.f) ? o.x : 0.01f * o.x; o.x += bfl(skv.x);
  o.y = (ayA + ayB) * inv + bv.y; o.y = (o.y > 0.f) ? o.y : 0.01f * o.y; o.y += bfh(skv.x);
  o.z = (azA + azB) * inv + bv.z; o.z = (o.z > 0.f) ? o.z : 0.01f * o.z; o.z += bfl(skv.y);
  o.w = (awA + awB) * inv + bv.w; o.w = (o.w > 0.f) ? o.w : 0.01f * o.w; o.w += bfh(skv.y);
  *(float4*)(out + (size_t)node * 256 + lane * 4) = o;
}

extern "C" void kernel_launch(void* const* d_in, const int* in_sizes, int n_in,
                              void* d_out, int out_size, void* d_ws, size_t ws_size,
                              hipStream_t stream) {
  const float* x = (const float*)d_in[0];
  const float* Wl = (const float*)d_in[1];
  const float* Wr = (const float*)d_in[2];
  const float* att = (const float*)d_in[3];
  const float* bias = (const float*)d_in[4];
  const float* Wskip = (const float*)d_in[5];
  const int* ei = (const int*)d_in[6];
  float* out = (float*)d_out;

  char* w = (char*)d_ws;
  size_t off = 0;
  auto alloc = [&](size_t bytes) {
    void* p = w + off;
    off = (off + bytes + 255) & ~(size_t)255;
    return p;
  };
  unsigned short* wb = (unsigned short*)alloc((size_t)768 * 256 * 2);
  unsigned short* xlb = (unsigned short*)alloc((size_t)NN * 256 * 2);
  unsigned short* zb = (unsigned short*)alloc((size_t)NN * 512 * 2);
  float* av6 = (float*)alloc(256 * 4);
  float* av04 = (float*)alloc(256 * 4);
  int* counts = (int*)alloc((size_t)NN * 4);
  int* partial = (int*)alloc((size_t)NN * 4);
  int* blockSums = (int*)alloc((size_t)SCAN_BLOCKS * 4);
  int* ptr = (int*)alloc((size_t)(NN + 1) * 4);
  int* cursor = (int*)alloc((size_t)NN * 4);
  int* csr = (int*)alloc((size_t)(EE + NN) * 4);
  if (ws_size < off) return;  // clean failure signal (out stays zero)

  hipMemsetAsync(counts, 0, (size_t)NN * 4, stream);
  k_prep<<<193 + 3125, 256, 0, stream>>>((const float4*)Wl, (const float4*)Wr,
                                         (const float4*)Wskip, att, ei,
                                         (uint2*)wb, av6, av04, counts);
  k_scan1<<<SCAN_BLOCKS, 1024, 0, stream>>>(counts, partial, blockSums);
  k_scan3<<<SCAN_BLOCKS, 1024, 0, stream>>>(partial, blockSums, ptr, cursor, csr);
  dim3 g(6, (NN + 127) / 128);
  k_gemm<<<g, 256, 0, stream>>>(x, wb, xlb, zb);
  k_scatter<<<(EE / 2 + 255) / 256, 256, 0, stream>>>(ei, cursor, csr);
  k_agg<<<(NN + 3) / 4, 256, 0, stream>>>((const uint2*)xlb, (const uint2*)zb,
                                          ptr, csr, av6, av04, bias, out);
}

// Round 10
// 217.130 us; speedup vs baseline: 1.0953x; 1.0953x over previous
//
#include <hip/hip_runtime.h>

#define NN 50000
#define EE 800000
#define SCAN_BLOCKS 49  // 49*1024 >= 50000
#define LOG2E 1.44269504088896340736f
#define NWG 2346        // 6 col-panels * 391 row-tiles
#define XQ 293          // NWG/8
#define XR 2            // NWG%8

typedef __attribute__((ext_vector_type(4))) float f32x4;
typedef __attribute__((ext_vector_type(8))) short bf16x8;
typedef unsigned int u32;
#define GLOBAL_AS __attribute__((address_space(1)))
#define LDS_AS __attribute__((address_space(3)))

static __device__ __forceinline__ u32 cvtpk_bf16(float lo, float hi) {
  u32 r;
  asm("v_cvt_pk_bf16_f32 %0, %1, %2" : "=v"(r) : "v"(lo), "v"(hi));
  return r;
}
static __device__ __forceinline__ unsigned short f2bf_hw(float f) {
  return (unsigned short)cvtpk_bf16(f, 0.f);
}
static __device__ __forceinline__ float bfl(unsigned int u) { return __uint_as_float(u << 16); }
static __device__ __forceinline__ float bfh(unsigned int u) { return __uint_as_float(u & 0xFFFF0000u); }

// ---- fused prep: conv x->bf16 | conv W->bf16 | att scales | edge histogram ----
__global__ void k_prep(const float4* __restrict__ x4,
                       const float4* __restrict__ Wl, const float4* __restrict__ Wr,
                       const float4* __restrict__ Ws, const float* __restrict__ att,
                       const int* __restrict__ ei,
                       uint2* __restrict__ xb2, uint2* __restrict__ wb2,
                       float* __restrict__ av6, float* __restrict__ av04,
                       int* __restrict__ counts) {
  int b = blockIdx.x;
  if (b < 12500) {
    int i = b * 256 + threadIdx.x;  // < 3200000 exactly
    float4 v = x4[i];
    uint2 o;
    o.x = cvtpk_bf16(v.x, v.y);
    o.y = cvtpk_bf16(v.z, v.w);
    xb2[i] = o;
  } else if (b < 12692) {
    int i = (b - 12500) * 256 + threadIdx.x;  // over 49152
    if (i < 49152) {
      int which = i >> 14;
      int idx = i & 16383;
      const float4* W = (which == 0) ? Wl : (which == 1) ? Wr : Ws;
      float4 v = W[idx];
      uint2 o;
      o.x = cvtpk_bf16(v.x, v.y);
      o.y = cvtpk_bf16(v.z, v.w);
      wb2[i] = o;
    }
  } else if (b == 12692) {
    float a = att[threadIdx.x];
    av6[threadIdx.x] = 0.6f * LOG2E * a;
    av04[threadIdx.x] = 0.4f * LOG2E * a;
  } else {
    int e = (b - 12693) * 256 + threadIdx.x;
    if (e < EE) atomicAdd(&counts[ei[EE + e]], 1);
  }
}

// ---- hierarchical scan (counts+1 folds in the self-loop) ----
__global__ __launch_bounds__(1024) void k_scan1(const int* __restrict__ counts,
                                                int* __restrict__ partial,
                                                int* __restrict__ blockSums) {
  __shared__ int tmp[1024];
  int t = threadIdx.x;
  int i = blockIdx.x * 1024 + t;
  int v = (i < NN) ? (counts[i] + 1) : 0;
  tmp[t] = v;
  __syncthreads();
  for (int off = 1; off < 1024; off <<= 1) {
    int u = (t >= off) ? tmp[t - off] : 0;
    __syncthreads();
    tmp[t] += u;
    __syncthreads();
  }
  if (i < NN) partial[i] = tmp[t] - v;  // exclusive within block
  if (t == 1023) blockSums[blockIdx.x] = tmp[1023];
}

// ---- block offsets (wave-reduced) -> ptr/cursor; self-loop placed here ----
__global__ __launch_bounds__(1024) void k_scan3(const int* __restrict__ partial,
                                                const int* __restrict__ blockSums,
                                                int* __restrict__ ptr,
                                                int* __restrict__ cursor,
                                                int* __restrict__ csr) {
  __shared__ int boff;
  if (threadIdx.x < 64) {
    int v = (threadIdx.x < blockIdx.x) ? blockSums[threadIdx.x] : 0;
    v += __shfl_xor(v, 1);
    v += __shfl_xor(v, 2);
    v += __shfl_xor(v, 4);
    v += __shfl_xor(v, 8);
    v += __shfl_xor(v, 16);
    v += __shfl_xor(v, 32);
    if (threadIdx.x == 0) boff = v;
  }
  __syncthreads();
  int i = blockIdx.x * 1024 + threadIdx.x;
  if (i < NN) {
    int v = partial[i] + boff;
    ptr[i] = v;
    csr[v] = i;          // self-loop occupies first slot
    cursor[i] = v + 1;   // real edges start after it
    if (i == NN - 1) ptr[NN] = EE + NN;
  }
}

// ---- scatter: own kernel (full occupancy), 4 edges/thread for atomic MLP ----
__global__ __launch_bounds__(256) void k_scatter(const int* __restrict__ ei,
                                                 int* __restrict__ cursor,
                                                 int* __restrict__ csr) {
  int t = blockIdx.x * 256 + threadIdx.x;
  if (t >= EE / 4) return;
  int e0 = t, e1 = t + EE / 4, e2 = t + EE / 2, e3 = t + 3 * (EE / 4);
  int d0 = ei[EE + e0];
  int d1 = ei[EE + e1];
  int d2 = ei[EE + e2];
  int d3 = ei[EE + e3];
  int p0 = atomicAdd(&cursor[d0], 1);
  int p1 = atomicAdd(&cursor[d1], 1);
  int p2 = atomicAdd(&cursor[d2], 1);
  int p3 = atomicAdd(&cursor[d3], 1);
  csr[p0] = ei[e0];
  csr[p1] = ei[e1];
  csr[p2] = ei[e2];
  csr[p3] = ei[e3];
}

// ---- GEMM: bf16 A/B via global_load_lds DMA; XCD-bijective swizzle so the 6
// col-panels of one A row-tile run on the SAME XCD (L2 reuse); LDS-transposed
// coalesced epilogue (reuses staging LDS as the C tile).
__global__ __launch_bounds__(256) void k_gemm(const unsigned short* __restrict__ xb,
                                              const unsigned short* __restrict__ wb,
                                              unsigned short* __restrict__ xlb,
                                              unsigned short* __restrict__ zb) {
  __shared__ alignas(16) unsigned short Sm[2][128 * 64];
  const int tid = threadIdx.x;
  const int lane = tid & 63;
  const int wave = tid >> 6;
  const int wr = wave >> 1, wc = wave & 1;
  // bijective XCD swizzle (m204): contiguous logical chunk per XCD
  int bid = blockIdx.x;
  int xcd = bid & 7, slot = bid >> 3;
  int wgid = (xcd < XR ? xcd * (XQ + 1) : XR * (XQ + 1) + (xcd - XR) * XQ) + slot;
  const int rbase = (wgid / 6) * 128;
  const int cbase = (wgid % 6) * 128;
  const int rl = lane & 15;
  const int q = lane >> 4;

  f32x4 acc[4][4];
#pragma unroll
  for (int a = 0; a < 4; ++a)
#pragma unroll
    for (int b = 0; b < 4; ++b) acc[a][b] = (f32x4){0.f, 0.f, 0.f, 0.f};

  for (int kt = 0; kt < 256; kt += 64) {
#pragma unroll
    for (int i = 0; i < 4; ++i) {
      int c = tid + i * 256;            // chunk id: 1024 chunks of 16B per buffer
      int row = c >> 3, kcx = c & 7;    // kcx = physical (linear LDS) slot
      int kc = kcx ^ (row & 7);         // logical k-chunk living in slot kcx
      int gr = rbase + row; if (gr > NN - 1) gr = NN - 1;
      int ldsoff = i * 4096 + wave * 1024;  // wave-uniform byte base
      __builtin_amdgcn_global_load_lds(
          (const GLOBAL_AS u32*)(xb + (size_t)gr * 256 + kt + kc * 8),
          (LDS_AS u32*)((LDS_AS char*)&Sm[0][0] + ldsoff), 16, 0, 0);
      __builtin_amdgcn_global_load_lds(
          (const GLOBAL_AS u32*)(wb + (size_t)(cbase + row) * 256 + kt + kc * 8),
          (LDS_AS u32*)((LDS_AS char*)&Sm[1][0] + ldsoff), 16, 0, 0);
    }
    __syncthreads();
#pragma unroll
    for (int ks = 0; ks < 2; ++ks) {
      bf16x8 af[4], bf[4];
      int kc = ks * 4 + q;
#pragma unroll
      for (int t = 0; t < 4; ++t) {
        int ra = wr * 64 + t * 16 + rl;
        af[t] = *(const bf16x8*)((const char*)&Sm[0][0] + ra * 128 + ((kc << 4) ^ ((ra & 7) << 4)));
        int rb = wc * 64 + t * 16 + rl;
        bf[t] = *(const bf16x8*)((const char*)&Sm[1][0] + rb * 128 + ((kc << 4) ^ ((rb & 7) << 4)));
      }
#pragma unroll
      for (int a = 0; a < 4; ++a)
#pragma unroll
        for (int b = 0; b < 4; ++b)
          acc[a][b] = __builtin_amdgcn_mfma_f32_16x16x32_bf16(af[a], bf[b], acc[a][b], 0, 0, 0);
    }
    __syncthreads();
  }
  // ---- epilogue: stage C tile in LDS (swizzled), then coalesced 16B stores ----
  char* Cs = (char*)&Sm[0][0];  // 32 KB = [128 rows][128 cols] bf16, XOR-swizzled
#pragma unroll
  for (int a = 0; a < 4; ++a) {
#pragma unroll
    for (int j = 0; j < 4; ++j) {
      int row = wr * 64 + a * 16 + q * 4 + j;
      int tag = ((row >> 2) & 7) << 5;
#pragma unroll
      for (int b = 0; b < 4; ++b) {
        int col = wc * 64 + b * 16 + rl;
        *(unsigned short*)(Cs + row * 256 + ((col * 2) ^ tag)) = f2bf_hw(acc[a][b][j]);
      }
    }
  }
  __syncthreads();
  const bool isxl = (cbase < 256);
  unsigned short* dst = isxl ? (xlb + cbase) : (zb + (cbase - 256));
  const int dstride = isxl ? 256 : 512;
#pragma unroll
  for (int it = 0; it < 8; ++it) {
    int id = it * 256 + tid;
    int row = id >> 4, cch = id & 15;   // 16 chunks of 8 cols per row
    int tag = ((row >> 2) & 7) << 5;
    uint4 v = *(const uint4*)(Cs + row * 256 + ((cch * 16) ^ tag));
    int grow = rbase + row;
    if (grow < NN)
      *(uint4*)(dst + (size_t)grow * dstride + cch * 8) = v;
  }
}

// ---- per-node FLAT-softmax aggregation + epilogue (4-deep, 32 VGPR) ----
#define LOGIT6(ex, ey, ez, ew, p)                                      \
  t = ex + xrx; p = a6.x * t;         p = fmaf(a04.x, fabsf(t), p);    \
  t = ey + xry; p = fmaf(a6.y, t, p); p = fmaf(a04.y, fabsf(t), p);    \
  t = ez + xrz; p = fmaf(a6.z, t, p); p = fmaf(a04.z, fabsf(t), p);    \
  t = ew + xrw; p = fmaf(a6.w, t, p); p = fmaf(a04.w, fabsf(t), p);

__global__ __launch_bounds__(256) void k_agg(const uint2* __restrict__ xl2,
                                             const uint2* __restrict__ zb2,
                                             const int* __restrict__ ptr,
                                             const int* __restrict__ csr,
                                             const float* __restrict__ av6,
                                             const float* __restrict__ av04,
                                             const float* __restrict__ bias,
                                             float* __restrict__ out) {
  int node = blockIdx.x * 4 + (threadIdx.x >> 6);
  if (node >= NN) return;
  int lane = threadIdx.x & 63;

  uint2 xrv = zb2[(size_t)node * 128 + lane];
  float xrx = bfl(xrv.x), xry = bfh(xrv.x), xrz = bfl(xrv.y), xrw = bfh(xrv.y);
  const float4 a6 = *(const float4*)(av6 + lane * 4);
  const float4 a04 = *(const float4*)(av04 + lane * 4);

  float sA = 0.f, axA = 0.f, ayA = 0.f, azA = 0.f, awA = 0.f;
  float sB = 0.f, axB = 0.f, ayB = 0.f, azB = 0.f, awB = 0.f;
  int beg = ptr[node], end = ptr[node + 1];
  int i = beg;
  for (; i + 4 <= end; i += 4) {
    int s0 = csr[i], s1 = csr[i + 1], s2 = csr[i + 2], s3 = csr[i + 3];
    uint2 v0 = xl2[(size_t)s0 * 64 + lane];
    uint2 v1 = xl2[(size_t)s1 * 64 + lane];
    uint2 v2 = xl2[(size_t)s2 * 64 + lane];
    uint2 v3 = xl2[(size_t)s3 * 64 + lane];
    float e0x = bfl(v0.x), e0y = bfh(v0.x), e0z = bfl(v0.y), e0w = bfh(v0.y);
    float e1x = bfl(v1.x), e1y = bfh(v1.x), e1z = bfl(v1.y), e1w = bfh(v1.y);
    float e2x = bfl(v2.x), e2y = bfh(v2.x), e2z = bfl(v2.y), e2w = bfh(v2.y);
    float e3x = bfl(v3.x), e3y = bfh(v3.x), e3z = bfl(v3.y), e3w = bfh(v3.y);
    float t, p0, p1, p2, p3;
    LOGIT6(e0x, e0y, e0z, e0w, p0)
    LOGIT6(e1x, e1y, e1z, e1w, p1)
    LOGIT6(e2x, e2y, e2z, e2w, p2)
    LOGIT6(e3x, e3y, e3z, e3w, p3)
    p0 += __shfl_xor(p0, 1); p1 += __shfl_xor(p1, 1);
    p2 += __shfl_xor(p2, 1); p3 += __shfl_xor(p3, 1);
    p0 += __shfl_xor(p0, 2); p1 += __shfl_xor(p1, 2);
    p2 += __shfl_xor(p2, 2); p3 += __shfl_xor(p3, 2);
    p0 += __shfl_xor(p0, 4); p1 += __shfl_xor(p1, 4);
    p2 += __shfl_xor(p2, 4); p3 += __shfl_xor(p3, 4);
    p0 = exp2f(p0); p1 = exp2f(p1); p2 = exp2f(p2); p3 = exp2f(p3);
    sA += p0;  axA += p0 * e0x; ayA += p0 * e0y; azA += p0 * e0z; awA += p0 * e0w;
    sB += p1;  axB += p1 * e1x; ayB += p1 * e1y; azB += p1 * e1z; awB += p1 * e1w;
    sA += p2;  axA += p2 * e2x; ayA += p2 * e2y; azA += p2 * e2z; awA += p2 * e2w;
    sB += p3;  axB += p3 * e3x; ayB += p3 * e3y; azB += p3 * e3z; awB += p3 * e3w;
  }
  for (; i < end; ++i) {
    int s0 = csr[i];
    uint2 v0 = xl2[(size_t)s0 * 64 + lane];
    float e0x = bfl(v0.x), e0y = bfh(v0.x), e0z = bfl(v0.y), e0w = bfh(v0.y);
    float t, p0;
    LOGIT6(e0x, e0y, e0z, e0w, p0)
    p0 += __shfl_xor(p0, 1);
    p0 += __shfl_xor(p0, 2);
    p0 += __shfl_xor(p0, 4);
    p0 = exp2f(p0);
    sA += p0;  axA += p0 * e0x; ayA += p0 * e0y; azA += p0 * e0z; awA += p0 * e0w;
  }
  float inv = 1.f / (sA + sB);
  uint2 skv = zb2[(size_t)node * 128 + 64 + lane];
  const float4 bv = *(const float4*)(bias + lane * 4);
  float4 o;
  o.x = (axA + axB) * inv + bv.x; o.x = (o.x > 0.f) ? o.x : 0.01f * o.x; o.x += bfl(skv.x);
  o.y = (ayA + ayB) * inv + bv.y; o.y = (o.y > 0.f) ? o.y : 0.01f * o.y; o.y += bfh(skv.x);
  o.z = (azA + azB) * inv + bv.z; o.z = (o.z > 0.f) ? o.z : 0.01f * o.z; o.z += bfl(skv.y);
  o.w = (awA + awB) * inv + bv.w; o.w = (o.w > 0.f) ? o.w : 0.01f * o.w; o.w += bfh(skv.y);
  *(float4*)(out + (size_t)node * 256 + lane * 4) = o;
}

extern "C" void kernel_launch(void* const* d_in, const int* in_sizes, int n_in,
                              void* d_out, int out_size, void* d_ws, size_t ws_size,
                              hipStream_t stream) {
  const float* x = (const float*)d_in[0];
  const float* Wl = (const float*)d_in[1];
  const float* Wr = (const float*)d_in[2];
  const float* att = (const float*)d_in[3];
  const float* bias = (const float*)d_in[4];
  const float* Wskip = (const float*)d_in[5];
  const int* ei = (const int*)d_in[6];
  float* out = (float*)d_out;

  char* w = (char*)d_ws;
  size_t off = 0;
  auto alloc = [&](size_t bytes) {
    void* p = w + off;
    off = (off + bytes + 255) & ~(size_t)255;
    return p;
  };
  unsigned short* xb = (unsigned short*)alloc((size_t)NN * 256 * 2);
  unsigned short* wb = (unsigned short*)alloc((size_t)768 * 256 * 2);
  unsigned short* xlb = (unsigned short*)alloc((size_t)NN * 256 * 2);
  unsigned short* zb = (unsigned short*)alloc((size_t)NN * 512 * 2);
  float* av6 = (float*)alloc(256 * 4);
  float* av04 = (float*)alloc(256 * 4);
  int* counts = (int*)alloc((size_t)NN * 4);
  int* partial = (int*)alloc((size_t)NN * 4);
  int* blockSums = (int*)alloc((size_t)SCAN_BLOCKS * 4);
  int* ptr = (int*)alloc((size_t)(NN + 1) * 4);
  int* cursor = (int*)alloc((size_t)NN * 4);
  int* csr = (int*)alloc((size_t)(EE + NN) * 4);
  if (ws_size < off) return;  // clean failure signal (out stays zero)

  hipMemsetAsync(counts, 0, (size_t)NN * 4, stream);
  k_prep<<<12693 + 3125, 256, 0, stream>>>((const float4*)x, (const float4*)Wl,
                                           (const float4*)Wr, (const float4*)Wskip,
                                           att, ei, (uint2*)xb, (uint2*)wb,
                                           av6, av04, counts);
  k_scan1<<<SCAN_BLOCKS, 1024, 0, stream>>>(counts, partial, blockSums);
  k_scan3<<<SCAN_BLOCKS, 1024, 0, stream>>>(partial, blockSums, ptr, cursor, csr);
  k_gemm<<<NWG, 256, 0, stream>>>(xb, wb, xlb, zb);
  k_scatter<<<(EE / 4 + 255) / 256, 256, 0, stream>>>(ei, cursor, csr);
  k_agg<<<(NN + 3) / 4, 256, 0, stream>>>((const uint2*)xlb, (const uint2*)zb,
                                          ptr, csr, av6, av04, bias, out);
}